// Round 4
// baseline (375.799 us; speedup 1.0000x reference)
//
#include <hip/hip_runtime.h>
#include <hip/hip_fp16.h>

#define FDIM 128
#define HEADS 4
#define CD 32
#define BM 64

typedef __attribute__((ext_vector_type(8))) short bfrag;   // 8 bf16 (4 VGPRs)
typedef __attribute__((ext_vector_type(4))) float ffrag;   // 4 f32 accum

static __device__ __forceinline__ unsigned short f2bf(float v) {
    unsigned u = __float_as_uint(v);
    u += 0x7FFF + ((u >> 16) & 1);          // round-nearest-even
    return (unsigned short)(u >> 16);
}
static __device__ __forceinline__ float bf2f(unsigned short u) {
    return __uint_as_float(((unsigned)u) << 16);
}

// K0: split W into bf16 hi/lo, transpose to [n][k].
__global__ __launch_bounds__(256) void k_wsplit(const float* __restrict__ w,
                                                unsigned short* __restrict__ wt_hi,
                                                unsigned short* __restrict__ wt_lo)
{
    int i = blockIdx.x * 256 + threadIdx.x;      // 16384 elements, coalesced read
    float v = w[i];
    unsigned short h = f2bf(v);
    float r = v - bf2f(h);
    int k = i >> 7, n = i & 127;
    wt_hi[n * FDIM + k] = h;
    wt_lo[n * FDIM + k] = f2bf(r);
}

// K1: MFMA GEMM (split bf16: hi*hi + hi*lo + lo*hi ~= fp32) + logits.
// Prologue zeroes seg (N*4 f32) + cnt (N ints) via grid-stride.
__global__ __launch_bounds__(256) void k_gemm(const float* __restrict__ x,
                                              const unsigned short* __restrict__ wt_hi,
                                              const unsigned short* __restrict__ wt_lo,
                                              const float* __restrict__ att,
                                              unsigned short* __restrict__ xwh,
                                              float* __restrict__ a_src,
                                              float* __restrict__ a_dst,
                                              float4* __restrict__ zero_base,
                                              int nz4, int N)
{
    __shared__ float accs[BM * 132];     // 64 rows x 128 cols, stride 132 (33.8KB)
    __shared__ float attl[HEADS * 2 * CD];
    int t = threadIdx.x;
    int row0 = blockIdx.x * BM;
    for (int i = blockIdx.x * 256 + t; i < nz4; i += gridDim.x * 256)
        zero_base[i] = make_float4(0.f, 0.f, 0.f, 0.f);
    attl[t] = att[t];

    int l = t & 63, wv = t >> 6;
    int la = l & 15, lr = l >> 4;
    int arow = row0 + wv * 16 + la;
    bool aval = arow < N;
    const float* xbase = x + (size_t)arow * FDIM + lr * 8;

    ffrag acc[8] = {};
#pragma unroll
    for (int ks = 0; ks < 4; ks++) {
        float xv[8] = {0.f, 0.f, 0.f, 0.f, 0.f, 0.f, 0.f, 0.f};
        if (aval) {
            float4 f0 = *(const float4*)(xbase + ks * 32);
            float4 f1 = *(const float4*)(xbase + ks * 32 + 4);
            xv[0] = f0.x; xv[1] = f0.y; xv[2] = f0.z; xv[3] = f0.w;
            xv[4] = f1.x; xv[5] = f1.y; xv[6] = f1.z; xv[7] = f1.w;
        }
        bfrag ah, al;
#pragma unroll
        for (int j = 0; j < 8; j++) {
            unsigned short h = f2bf(xv[j]);
            ah[j] = (short)h;
            al[j] = (short)f2bf(xv[j] - bf2f(h));
        }
        int boff = ks * 32 + lr * 8;
#pragma unroll
        for (int ct = 0; ct < 8; ct++) {
            int o = (ct * 16 + la) * FDIM + boff;
            bfrag bh = *(const bfrag*)(wt_hi + o);
            bfrag bl = *(const bfrag*)(wt_lo + o);
            acc[ct] = __builtin_amdgcn_mfma_f32_16x16x32_bf16(ah, bh, acc[ct], 0, 0, 0);
            acc[ct] = __builtin_amdgcn_mfma_f32_16x16x32_bf16(ah, bl, acc[ct], 0, 0, 0);
            acc[ct] = __builtin_amdgcn_mfma_f32_16x16x32_bf16(al, bh, acc[ct], 0, 0, 0);
        }
    }

#pragma unroll
    for (int i = 0; i < 4; i++) {
        int r = row0 + wv * 16 + lr * 4 + i;
        if (r < N) {
            uint2 pa, pb;
            pa.x = (unsigned)f2bf(acc[0][i]) | ((unsigned)f2bf(acc[2][i]) << 16);
            pa.y = (unsigned)f2bf(acc[4][i]) | ((unsigned)f2bf(acc[6][i]) << 16);
            pb.x = (unsigned)f2bf(acc[1][i]) | ((unsigned)f2bf(acc[3][i]) << 16);
            pb.y = (unsigned)f2bf(acc[5][i]) | ((unsigned)f2bf(acc[7][i]) << 16);
            *(uint2*)&xwh[(size_t)r * FDIM + la * 4] = pa;
            *(uint2*)&xwh[(size_t)r * FDIM + 64 + la * 4] = pb;
        }
    }
#pragma unroll
    for (int ct = 0; ct < 8; ct++)
#pragma unroll
        for (int i = 0; i < 4; i++)
            accs[(wv * 16 + lr * 4 + i) * 132 + ct * 16 + la] = acc[ct][i];
    __syncthreads();
    int row = t >> 2, h = t & 3;
    const float* ap = &attl[h * 2 * CD];
    const float* xr = &accs[row * 132 + h * CD];
    float s = 0.f, d = 0.f;
#pragma unroll 8
    for (int c = 0; c < CD; c++) { float v = xr[c]; s += v * ap[c]; d += v * ap[CD + c]; }
    int n = row0 + row;
    if (n < N) { a_src[n * 4 + h] = s; a_dst[n * 4 + h] = d; }
}

// K2: lane-per-(edge,head): seg atomics coalesce per-instruction (4 lanes = one 16B
// sector). Also folds the destination in-degree histogram (1 atomic per edge).
__global__ __launch_bounds__(256) void k_esum(const int* __restrict__ ei, int E,
                                              const float* __restrict__ a_src,
                                              const float* __restrict__ a_dst,
                                              float* __restrict__ seg,
                                              int* __restrict__ cnt,
                                              __half* __restrict__ ealpha)
{
    int gid = blockIdx.x * 256 + threadIdx.x;
    if (gid >= E * HEADS) return;
    int e = gid >> 2, h = gid & 3;
    int r = ei[e], cl = ei[E + e];
    float a = a_src[r * 4 + h] + a_dst[cl * 4 + h];
    a = a >= 0.f ? a : 0.2f * a;
    float ex = __expf(a);
    ealpha[gid] = __float2half(ex);
    atomicAdd(&seg[r * 4 + h], ex);
    if (h == 0) atomicAdd(&cnt[cl], 1);
}

// K3: single-block exclusive scan over cnt[0..N) -> base + cursor copy.
__global__ __launch_bounds__(1024) void k_scanN(const int* __restrict__ cnt,
                                                int* __restrict__ base,
                                                int* __restrict__ cursor, int N, int E)
{
    __shared__ int wsum[16];
    int t = threadIdx.x, lane = t & 63, w = t >> 6;
    int span = (N + 1023) / 1024;
    int s0 = t * span, s1 = min(s0 + span, N);
    int sum = 0;
    for (int i = s0; i < s1; i++) sum += cnt[i];
    int x = sum;
#pragma unroll
    for (int d = 1; d < 64; d <<= 1) { int y = __shfl_up(x, d, 64); if (lane >= d) x += y; }
    if (lane == 63) wsum[w] = x;
    __syncthreads();
    int woff = 0;
    for (int i = 0; i < w; i++) woff += wsum[i];
    int run = woff + x - sum;                  // exclusive prefix at s0
    for (int i = s0; i < s1; i++) { base[i] = run; cursor[i] = run; run += cnt[i]; }
    if (t == 1023) base[N] = E;
}

// K4: normalize alpha (0.25 head-mean folded in) and place record at the
// destination-CSR slot. rec = (r, na01, na23, 0), 16B.
__global__ __launch_bounds__(256) void k_place(const int* __restrict__ ei, int E,
                                               const __half* __restrict__ ealpha,
                                               const float* __restrict__ seg,
                                               int* __restrict__ cursor,
                                               uint4* __restrict__ recs)
{
    int e = blockIdx.x * 256 + threadIdx.x;
    if (e >= E) return;
    int r = ei[e], cl = ei[E + e];
    uint2 a = *(const uint2*)(ealpha + (size_t)e * 4);
    __half2 e01 = *(__half2*)&a.x, e23 = *(__half2*)&a.y;
    float4 s4 = *(const float4*)&seg[r * 4];
    float na0 = 0.25f * __low2float(e01) / (s4.x + 1e-16f);
    float na1 = 0.25f * __high2float(e01) / (s4.y + 1e-16f);
    float na2 = 0.25f * __low2float(e23) / (s4.z + 1e-16f);
    float na3 = 0.25f * __high2float(e23) / (s4.w + 1e-16f);
    __half2 n01 = __floats2half2_rn(na0, na1), n23 = __floats2half2_rn(na2, na3);
    int pos = atomicAdd(&cursor[cl], 1);
    recs[pos] = make_uint4((unsigned)r, *(unsigned*)&n01, *(unsigned*)&n23, 0u);
}

// K5: per-destination aggregation, NO atomics. 16 lanes per node; each lane owns
// channels 2*c2, 2*c2+1 (all 4 heads), accumulates in fp32, writes out + bias.
__global__ __launch_bounds__(256) void k_aggregate(const uint4* __restrict__ recs,
                                                   const int* __restrict__ base,
                                                   const unsigned short* __restrict__ xwh,
                                                   const float* __restrict__ bias,
                                                   float* __restrict__ out, int N)
{
    int t = threadIdx.x;
    int ln = t >> 4, c2 = t & 15;             // 16 nodes/block, 16 lanes/node
    int cl = blockIdx.x * 16 + ln;
    if (cl >= N) return;
    int lo = base[cl], hi = base[cl + 1];
    float acc0 = 0.f, acc1 = 0.f;
    for (int i = lo; i < hi; i++) {
        uint4 rec = recs[i];                  // same addr across 16 lanes (broadcast)
        int r = (int)rec.x;
        __half2 h01 = *(__half2*)&rec.y;
        __half2 h23 = *(__half2*)&rec.z;
        float na0 = __low2float(h01), na1 = __high2float(h01);
        float na2 = __low2float(h23), na3 = __high2float(h23);
        uint4 q = ((const uint4*)(xwh + (size_t)r * FDIM))[c2];
        acc0 += na0 * bf2f((unsigned short)(q.x & 0xFFFF)) + na1 * bf2f((unsigned short)(q.x >> 16))
              + na2 * bf2f((unsigned short)(q.y & 0xFFFF)) + na3 * bf2f((unsigned short)(q.y >> 16));
        acc1 += na0 * bf2f((unsigned short)(q.z & 0xFFFF)) + na1 * bf2f((unsigned short)(q.z >> 16))
              + na2 * bf2f((unsigned short)(q.w & 0xFFFF)) + na3 * bf2f((unsigned short)(q.w >> 16));
    }
    float2 b = ((const float2*)bias)[c2];
    ((float2*)out)[(size_t)cl * 16 + c2] = make_float2(acc0 + b.x, acc1 + b.y);
}

extern "C" void kernel_launch(void* const* d_in, const int* in_sizes, int n_in,
                              void* d_out, int out_size, void* d_ws, size_t ws_size,
                              hipStream_t stream)
{
    const float* x    = (const float*)d_in[0];
    const int*   ei   = (const int*)d_in[1];
    const float* w    = (const float*)d_in[2];
    const float* att  = (const float*)d_in[3];
    const float* bias = (const float*)d_in[4];
    float* out = (float*)d_out;
    int N = in_sizes[0] / FDIM;
    int E = in_sizes[1] / 2;

    // layout (16B-aligned where vector loads require it)
    unsigned short* xwh = (unsigned short*)d_ws;              // N*128 bf16  (12.8 MB)
    uint4* recs     = (uint4*)(xwh + (size_t)N * FDIM);       // E*16B dst-sorted records
    __half* ealpha  = (__half*)(recs + (size_t)E);            // E*4 fp16
    float* a_src    = (float*)(ealpha + (size_t)E * HEADS);   // N*4 f32
    float* a_dst    = a_src + (size_t)N * HEADS;              // N*4 f32
    float* seg      = a_dst + (size_t)N * HEADS;              // N*4 f32   (zeroed)
    int*   cnt      = (int*)(seg + (size_t)N * HEADS);        // N+4 int   (zeroed, contig)
    int*   base     = cnt + N + 4;                            // N+1 int
    int*   cursor   = base + N + 4;                           // N int
    unsigned short* wt_hi = (unsigned short*)(cursor + N + 4);// 128*128 bf16
    unsigned short* wt_lo = wt_hi + FDIM * FDIM;              // 128*128 bf16

    int nz4 = (N * 5 + 19) / 4;   // seg N*4 f32 + cnt N+4 ints, float4 units

    k_wsplit<<<(FDIM * FDIM) / 256, 256, 0, stream>>>(w, wt_hi, wt_lo);
    k_gemm<<<(N + BM - 1) / BM, 256, 0, stream>>>(x, wt_hi, wt_lo, att, xwh, a_src, a_dst,
                                                  (float4*)seg, nz4, N);
    k_esum<<<(E * HEADS + 255) / 256, 256, 0, stream>>>(ei, E, a_src, a_dst, seg, cnt, ealpha);
    k_scanN<<<1, 1024, 0, stream>>>(cnt, base, cursor, N, E);
    k_place<<<(E + 255) / 256, 256, 0, stream>>>(ei, E, ealpha, seg, cursor, recs);
    k_aggregate<<<(N + 15) / 16, 256, 0, stream>>>(recs, base, xwh, bias, out, N);
}

// Round 5
// 283.445 us; speedup vs baseline: 1.3258x; 1.3258x over previous
//
#include <hip/hip_runtime.h>
#include <hip/hip_fp16.h>

#define FDIM 128
#define HEADS 4
#define CD 32
#define BM 64
#define SCB 2048        // cnt elements per scan block

typedef __attribute__((ext_vector_type(8))) short bfrag;   // 8 bf16 (4 VGPRs)
typedef __attribute__((ext_vector_type(4))) float ffrag;   // 4 f32 accum

static __device__ __forceinline__ unsigned short f2bf(float v) {
    unsigned u = __float_as_uint(v);
    u += 0x7FFF + ((u >> 16) & 1);          // round-nearest-even
    return (unsigned short)(u >> 16);
}
static __device__ __forceinline__ float bf2f(unsigned short u) {
    return __uint_as_float(((unsigned)u) << 16);
}

// K0: split W into bf16 hi/lo, transpose to [n][k].
__global__ __launch_bounds__(256) void k_wsplit(const float* __restrict__ w,
                                                unsigned short* __restrict__ wt_hi,
                                                unsigned short* __restrict__ wt_lo)
{
    int i = blockIdx.x * 256 + threadIdx.x;      // 16384 elements, coalesced read
    float v = w[i];
    unsigned short h = f2bf(v);
    float r = v - bf2f(h);
    int k = i >> 7, n = i & 127;
    wt_hi[n * FDIM + k] = h;
    wt_lo[n * FDIM + k] = f2bf(r);
}

// K1: MFMA GEMM (split bf16: hi*hi + hi*lo + lo*hi ~= fp32) + logits.
// Prologue zeroes seg (N*4 f32) + cnt (N ints) via grid-stride.
__global__ __launch_bounds__(256) void k_gemm(const float* __restrict__ x,
                                              const unsigned short* __restrict__ wt_hi,
                                              const unsigned short* __restrict__ wt_lo,
                                              const float* __restrict__ att,
                                              unsigned short* __restrict__ xwh,
                                              float* __restrict__ a_src,
                                              float* __restrict__ a_dst,
                                              float4* __restrict__ zero_base,
                                              int nz4, int N)
{
    __shared__ float accs[BM * 132];     // 64 rows x 128 cols, stride 132 (33.8KB)
    __shared__ float attl[HEADS * 2 * CD];
    int t = threadIdx.x;
    int row0 = blockIdx.x * BM;
    for (int i = blockIdx.x * 256 + t; i < nz4; i += gridDim.x * 256)
        zero_base[i] = make_float4(0.f, 0.f, 0.f, 0.f);
    attl[t] = att[t];

    int l = t & 63, wv = t >> 6;
    int la = l & 15, lr = l >> 4;
    int arow = row0 + wv * 16 + la;
    bool aval = arow < N;
    const float* xbase = x + (size_t)arow * FDIM + lr * 8;

    ffrag acc[8] = {};
#pragma unroll
    for (int ks = 0; ks < 4; ks++) {
        float xv[8] = {0.f, 0.f, 0.f, 0.f, 0.f, 0.f, 0.f, 0.f};
        if (aval) {
            float4 f0 = *(const float4*)(xbase + ks * 32);
            float4 f1 = *(const float4*)(xbase + ks * 32 + 4);
            xv[0] = f0.x; xv[1] = f0.y; xv[2] = f0.z; xv[3] = f0.w;
            xv[4] = f1.x; xv[5] = f1.y; xv[6] = f1.z; xv[7] = f1.w;
        }
        bfrag ah, al;
#pragma unroll
        for (int j = 0; j < 8; j++) {
            unsigned short h = f2bf(xv[j]);
            ah[j] = (short)h;
            al[j] = (short)f2bf(xv[j] - bf2f(h));
        }
        int boff = ks * 32 + lr * 8;
#pragma unroll
        for (int ct = 0; ct < 8; ct++) {
            int o = (ct * 16 + la) * FDIM + boff;
            bfrag bh = *(const bfrag*)(wt_hi + o);
            bfrag bl = *(const bfrag*)(wt_lo + o);
            acc[ct] = __builtin_amdgcn_mfma_f32_16x16x32_bf16(ah, bh, acc[ct], 0, 0, 0);
            acc[ct] = __builtin_amdgcn_mfma_f32_16x16x32_bf16(ah, bl, acc[ct], 0, 0, 0);
            acc[ct] = __builtin_amdgcn_mfma_f32_16x16x32_bf16(al, bh, acc[ct], 0, 0, 0);
        }
    }

#pragma unroll
    for (int i = 0; i < 4; i++) {
        int r = row0 + wv * 16 + lr * 4 + i;
        if (r < N) {
            uint2 pa, pb;
            pa.x = (unsigned)f2bf(acc[0][i]) | ((unsigned)f2bf(acc[2][i]) << 16);
            pa.y = (unsigned)f2bf(acc[4][i]) | ((unsigned)f2bf(acc[6][i]) << 16);
            pb.x = (unsigned)f2bf(acc[1][i]) | ((unsigned)f2bf(acc[3][i]) << 16);
            pb.y = (unsigned)f2bf(acc[5][i]) | ((unsigned)f2bf(acc[7][i]) << 16);
            *(uint2*)&xwh[(size_t)r * FDIM + la * 4] = pa;
            *(uint2*)&xwh[(size_t)r * FDIM + 64 + la * 4] = pb;
        }
    }
#pragma unroll
    for (int ct = 0; ct < 8; ct++)
#pragma unroll
        for (int i = 0; i < 4; i++)
            accs[(wv * 16 + lr * 4 + i) * 132 + ct * 16 + la] = acc[ct][i];
    __syncthreads();
    int row = t >> 2, h = t & 3;
    const float* ap = &attl[h * 2 * CD];
    const float* xr = &accs[row * 132 + h * CD];
    float s = 0.f, d = 0.f;
#pragma unroll 8
    for (int c = 0; c < CD; c++) { float v = xr[c]; s += v * ap[c]; d += v * ap[CD + c]; }
    int n = row0 + row;
    if (n < N) { a_src[n * 4 + h] = s; a_dst[n * 4 + h] = d; }
}

// K2: lane-per-(edge,head): seg atomics coalesce per-instruction (4 lanes = one 16B
// sector). Also folds the destination in-degree histogram (1 atomic per edge).
__global__ __launch_bounds__(256) void k_esum(const int* __restrict__ ei, int E,
                                              const float* __restrict__ a_src,
                                              const float* __restrict__ a_dst,
                                              float* __restrict__ seg,
                                              int* __restrict__ cnt,
                                              __half* __restrict__ ealpha)
{
    int gid = blockIdx.x * 256 + threadIdx.x;
    if (gid >= E * HEADS) return;
    int e = gid >> 2, h = gid & 3;
    int r = ei[e], cl = ei[E + e];
    float a = a_src[r * 4 + h] + a_dst[cl * 4 + h];
    a = a >= 0.f ? a : 0.2f * a;
    float ex = __expf(a);
    ealpha[gid] = __float2half(ex);
    atomicAdd(&seg[r * 4 + h], ex);
    if (h == 0) atomicAdd(&cnt[cl], 1);
}

// K3a: per-chunk reduction: blkSum[b] = sum of cnt[b*SCB .. b*SCB+SCB)
__global__ __launch_bounds__(256) void k_scan1(const int* __restrict__ cnt,
                                               int* __restrict__ blkSum, int N)
{
    __shared__ int ws[4];
    int t = threadIdx.x;
    int i0 = blockIdx.x * SCB + t * 8;
    int s = 0;
#pragma unroll
    for (int j = 0; j < 8; j++) { int i = i0 + j; if (i < N) s += cnt[i]; }
#pragma unroll
    for (int d = 1; d < 64; d <<= 1) s += __shfl_xor(s, d, 64);
    if ((t & 63) == 0) ws[t >> 6] = s;
    __syncthreads();
    if (t == 0) blkSum[blockIdx.x] = ws[0] + ws[1] + ws[2] + ws[3];
}

// K3b: one wave scans the (<=64) block sums -> exclusive blkOff; base[N] = E.
__global__ void k_scan2(const int* __restrict__ blkSum, int* __restrict__ blkOff,
                        int* __restrict__ base, int N, int E, int nsb)
{
    int t = threadIdx.x;   // 64 threads, one wave
    int v = (t < nsb) ? blkSum[t] : 0;
    int x = v;
#pragma unroll
    for (int d = 1; d < 64; d <<= 1) { int y = __shfl_up(x, d, 64); if (t >= d) x += y; }
    if (t < nsb) blkOff[t] = x - v;
    if (t == 63) base[N] = E;
}

// K3c: per-chunk exclusive scan + block offset -> base, cursor.
__global__ __launch_bounds__(256) void k_scan3(const int* __restrict__ cnt,
                                               const int* __restrict__ blkOff,
                                               int* __restrict__ base,
                                               int* __restrict__ cursor, int N)
{
    __shared__ int ws[4];
    int t = threadIdx.x, lane = t & 63, w = t >> 6;
    int i0 = blockIdx.x * SCB + t * 8;
    int v[8], s = 0;
#pragma unroll
    for (int j = 0; j < 8; j++) { int i = i0 + j; v[j] = (i < N) ? cnt[i] : 0; s += v[j]; }
    int x = s;
#pragma unroll
    for (int d = 1; d < 64; d <<= 1) { int y = __shfl_up(x, d, 64); if (lane >= d) x += y; }
    int texcl = x - s;
    if (lane == 63) ws[w] = x;
    __syncthreads();
    int woff = 0;
    for (int i = 0; i < w; i++) woff += ws[i];
    int run = blkOff[blockIdx.x] + woff + texcl;
#pragma unroll
    for (int j = 0; j < 8; j++) {
        int i = i0 + j;
        if (i < N) { base[i] = run; cursor[i] = run; run += v[j]; }
    }
}

// K4: normalize alpha (0.25 head-mean folded in) and place record at the
// destination-CSR slot. rec = (r, na01, na23, 0), 16B.
__global__ __launch_bounds__(256) void k_place(const int* __restrict__ ei, int E,
                                               const __half* __restrict__ ealpha,
                                               const float* __restrict__ seg,
                                               int* __restrict__ cursor,
                                               uint4* __restrict__ recs)
{
    int e = blockIdx.x * 256 + threadIdx.x;
    if (e >= E) return;
    int r = ei[e], cl = ei[E + e];
    uint2 a = *(const uint2*)(ealpha + (size_t)e * 4);
    __half2 e01 = *(__half2*)&a.x, e23 = *(__half2*)&a.y;
    float4 s4 = *(const float4*)&seg[r * 4];
    float na0 = 0.25f * __low2float(e01) / (s4.x + 1e-16f);
    float na1 = 0.25f * __high2float(e01) / (s4.y + 1e-16f);
    float na2 = 0.25f * __low2float(e23) / (s4.z + 1e-16f);
    float na3 = 0.25f * __high2float(e23) / (s4.w + 1e-16f);
    __half2 n01 = __floats2half2_rn(na0, na1), n23 = __floats2half2_rn(na2, na3);
    int pos = atomicAdd(&cursor[cl], 1);
    recs[pos] = make_uint4((unsigned)r, *(unsigned*)&n01, *(unsigned*)&n23, 0u);
}

// K5: per-destination aggregation, NO atomics. 16 lanes per node; each lane owns
// channels 2*c2, 2*c2+1 (all 4 heads), accumulates in fp32, writes out + bias.
__global__ __launch_bounds__(256) void k_aggregate(const uint4* __restrict__ recs,
                                                   const int* __restrict__ base,
                                                   const unsigned short* __restrict__ xwh,
                                                   const float* __restrict__ bias,
                                                   float* __restrict__ out, int N)
{
    int t = threadIdx.x;
    int ln = t >> 4, c2 = t & 15;             // 16 nodes/block, 16 lanes/node
    int cl = blockIdx.x * 16 + ln;
    if (cl >= N) return;
    int lo = base[cl], hi = base[cl + 1];
    float acc0 = 0.f, acc1 = 0.f;
    for (int i = lo; i < hi; i++) {
        uint4 rec = recs[i];                  // same addr across 16 lanes (broadcast)
        int r = (int)rec.x;
        __half2 h01 = *(__half2*)&rec.y;
        __half2 h23 = *(__half2*)&rec.z;
        float na0 = __low2float(h01), na1 = __high2float(h01);
        float na2 = __low2float(h23), na3 = __high2float(h23);
        uint4 q = ((const uint4*)(xwh + (size_t)r * FDIM))[c2];
        acc0 += na0 * bf2f((unsigned short)(q.x & 0xFFFF)) + na1 * bf2f((unsigned short)(q.x >> 16))
              + na2 * bf2f((unsigned short)(q.y & 0xFFFF)) + na3 * bf2f((unsigned short)(q.y >> 16));
        acc1 += na0 * bf2f((unsigned short)(q.z & 0xFFFF)) + na1 * bf2f((unsigned short)(q.z >> 16))
              + na2 * bf2f((unsigned short)(q.w & 0xFFFF)) + na3 * bf2f((unsigned short)(q.w >> 16));
    }
    float2 b = ((const float2*)bias)[c2];
    ((float2*)out)[(size_t)cl * 16 + c2] = make_float2(acc0 + b.x, acc1 + b.y);
}

extern "C" void kernel_launch(void* const* d_in, const int* in_sizes, int n_in,
                              void* d_out, int out_size, void* d_ws, size_t ws_size,
                              hipStream_t stream)
{
    const float* x    = (const float*)d_in[0];
    const int*   ei   = (const int*)d_in[1];
    const float* w    = (const float*)d_in[2];
    const float* att  = (const float*)d_in[3];
    const float* bias = (const float*)d_in[4];
    float* out = (float*)d_out;
    int N = in_sizes[0] / FDIM;
    int E = in_sizes[1] / 2;
    int nsb = (N + SCB - 1) / SCB;           // 25 for N=50000 (must be <= 64)

    // layout (16B-aligned where vector loads require it)
    unsigned short* xwh = (unsigned short*)d_ws;              // N*128 bf16  (12.8 MB)
    uint4* recs     = (uint4*)(xwh + (size_t)N * FDIM);       // E*16B dst-sorted records
    __half* ealpha  = (__half*)(recs + (size_t)E);            // E*4 fp16
    float* a_src    = (float*)(ealpha + (size_t)E * HEADS);   // N*4 f32
    float* a_dst    = a_src + (size_t)N * HEADS;              // N*4 f32
    float* seg      = a_dst + (size_t)N * HEADS;              // N*4 f32   (zeroed)
    int*   cnt      = (int*)(seg + (size_t)N * HEADS);        // N+4 int   (zeroed, contig)
    int*   base     = cnt + N + 4;                            // N+1 int
    int*   cursor   = base + N + 4;                           // N int
    int*   blkSum   = cursor + N + 4;                         // <=64 int
    int*   blkOff   = blkSum + 64;                            // <=64 int
    unsigned short* wt_hi = (unsigned short*)(blkOff + 64);   // 128*128 bf16
    unsigned short* wt_lo = wt_hi + FDIM * FDIM;              // 128*128 bf16

    int nz4 = (N * 5 + 19) / 4;   // seg N*4 f32 + cnt N+4 ints, float4 units

    k_wsplit<<<(FDIM * FDIM) / 256, 256, 0, stream>>>(w, wt_hi, wt_lo);
    k_gemm<<<(N + BM - 1) / BM, 256, 0, stream>>>(x, wt_hi, wt_lo, att, xwh, a_src, a_dst,
                                                  (float4*)seg, nz4, N);
    k_esum<<<(E * HEADS + 255) / 256, 256, 0, stream>>>(ei, E, a_src, a_dst, seg, cnt, ealpha);
    k_scan1<<<nsb, 256, 0, stream>>>(cnt, blkSum, N);
    k_scan2<<<1, 64, 0, stream>>>(blkSum, blkOff, base, N, E, nsb);
    k_scan3<<<nsb, 256, 0, stream>>>(cnt, blkOff, base, cursor, N);
    k_place<<<(E + 255) / 256, 256, 0, stream>>>(ei, E, ealpha, seg, cursor, recs);
    k_aggregate<<<(N + 15) / 16, 256, 0, stream>>>(recs, base, xwh, bias, out, N);
}